// Round 5
// baseline (660.571 us; speedup 1.0000x reference)
//
#include <hip/hip_runtime.h>
#include <hip/hip_fp16.h>

#define TSTEPS 276
#define NBATCH 32768
#define KDIM   4416   // 276*16
#define NPAD   320    // Wfc rows padded to 2*160
#define NOUT   276
#define GBM    128    // gemm block M (R5: 64 -> 128, halves B L2/L3 volume)
#define GBN    320    // gemm block N (full)
#define NCHUNK 138    // KDIM / 32
#define ROWBLK_ELE (138 * 4096)  // elements per 128-row block of H (138 k-tiles)
#define BTILE_ELE  (320 * 32)    // elements per k-tile of W2t (10240)
#define BUFB   28672  // gemm LDS bytes per pipe stage: A 8KB + B 20KB

typedef _Float16 half8 __attribute__((ext_vector_type(8)));
typedef float    f32x4 __attribute__((ext_vector_type(4)));

__device__ __forceinline__ float fast_sigmoid(float x) {
    float e = __builtin_amdgcn_exp2f(-1.4426950408889634f * x);
    return __builtin_amdgcn_rcpf(1.0f + e);
}
__device__ __forceinline__ float fast_tanh(float x) {
    float e = __builtin_amdgcn_exp2f(2.885390081777927f * x);
    return 1.0f - 2.0f * __builtin_amdgcn_rcpf(1.0f + e);
}

__device__ __forceinline__ void async_copy16(const void* g, void* l) {
    __builtin_amdgcn_global_load_lds(
        (const __attribute__((address_space(1))) void*)g,
        (__attribute__((address_space(3))) void*)l, 16, 0, 0);
}

// broadcast h from lane (lane&0x18)|j within each 8-lane group (BitMode swizzle)
#define HSWZ(dst, hb, j) dst = __int_as_float(__builtin_amdgcn_ds_swizzle(hb, ((j) << 5) | 0x18))

// ---------------- Kernel 1: bidirectional LSTM ----------------
// Issue-bound (VALUBusy ~100%). THIS ROUND: only the H tile height changes
// (64 -> 128 rows) to match GBM=128: Ht[b/128][k/32][128][32] fp16.
// Element (row bl, p=s*16+dir*8+j) -> (bl>>7)*ROWBLK + (p>>5)*4096 +
// (bl&127)*32 + (p&31). Write pattern quality identical (16 rows x 32B
// per block per step, neighbor blocks fill adjacent rows).
__global__ __launch_bounds__(256, 4) void lstm_kernel(
    const float* __restrict__ x,
    const float* __restrict__ Wih_f, const float* __restrict__ Whh_f,
    const float* __restrict__ bih_f, const float* __restrict__ bhh_f,
    const float* __restrict__ Wih_b, const float* __restrict__ Whh_b,
    const float* __restrict__ bih_b, const float* __restrict__ bhh_b,
    int row0, _Float16* __restrict__ Hout)
{
    const int tid = threadIdx.x;
    const int k   = tid & 7;
    const int rd  = blockIdx.x * 32 + (tid >> 3);
    const int bl  = rd >> 1;
    const int dir = rd & 1;
    const int bg  = row0 + bl;

    const float* Wih = dir ? Wih_b : Wih_f;
    const float* Whh = dir ? Whh_b : Whh_f;
    const float* bih = dir ? bih_b : bih_f;
    const float* bhh = dir ? bhh_b : bhh_f;

    float Wk[4][8], Wi0[4], Wi1[4], bs[4];
    #pragma unroll
    for (int g = 0; g < 4; ++g) {
        int row = g * 8 + k;                       // PyTorch gate order i,f,g,o
        #pragma unroll
        for (int j = 0; j < 8; ++j) Wk[g][j] = Whh[row * 8 + j];
        Wi0[g] = Wih[row * 2 + 0];
        Wi1[g] = Wih[row * 2 + 1];
        bs[g]  = bih[row] + bhh[row];
    }
    // pin every weight in an ArchVGPR: forbids rematerialization/reload
    #pragma unroll
    for (int g = 0; g < 4; ++g) {
        #pragma unroll
        for (int j = 0; j < 8; ++j) asm volatile("" : "+v"(Wk[g][j]));
        asm volatile("" : "+v"(Wi0[g]));
        asm volatile("" : "+v"(Wi1[g]));
        asm volatile("" : "+v"(bs[g]));
    }

    const float2* __restrict__ xrow = (const float2*)(x + (size_t)bg * (TSTEPS * 2));
    // tiled store base (128-row tiles); step s writes hp[(s&1)*16], advancing
    // one k-tile (4096 ele) after each odd s.
    _Float16* __restrict__ hp = Hout + (size_t)(bl >> 7) * ROWBLK_ELE
                                      + (bl & 127) * 32 + dir * 8 + k;

    float h = 0.0f, c = 0.0f;
    float2 xv = xrow[dir ? (TSTEPS - 1) : 0];
    #pragma unroll 2
    for (int s = 0; s < TSTEPS; ++s) {
        const int sn = (s + 1 < TSTEPS) ? (s + 1) : s;
        const float2 xv_n = xrow[dir ? (TSTEPS - 1 - sn) : sn];   // prefetch

        const int hb = __float_as_int(h);
        float hv[8];
        HSWZ(hv[0], hb, 0); HSWZ(hv[1], hb, 1); HSWZ(hv[2], hb, 2); HSWZ(hv[3], hb, 3);
        HSWZ(hv[4], hb, 4); HSWZ(hv[5], hb, 5); HSWZ(hv[6], hb, 6); HSWZ(hv[7], hb, 7);

        float a[4];
        #pragma unroll
        for (int g = 0; g < 4; ++g) {
            float acc = fmaf(xv.x, Wi0[g], bs[g]);
            acc = fmaf(xv.y, Wi1[g], acc);
            #pragma unroll
            for (int j = 0; j < 8; ++j) acc = fmaf(Wk[g][j], hv[j], acc);
            a[g] = acc;
        }
        const float ig = fast_sigmoid(a[0]);
        const float fg = fast_sigmoid(a[1]);
        const float gg = fast_tanh(a[2]);
        const float og = fast_sigmoid(a[3]);
        c = fmaf(fg, c, ig * gg);
        h = og * fast_tanh(c);

        hp[(s & 1) << 4] = (_Float16)h;            // kc = (s&1)*16 + dir*8 + j
        hp += (size_t)((s & 1) << 12);             // +4096 ele after odd steps
        xv = xv_n;
    }
}

// ---------------- Kernel 2: Wfc fp32 -> fp16, K-permutation + B-TILING ------
// (unchanged) W2t[k/32][320][32] fp16: one k-chunk of B = contiguous 20KB.
__global__ __launch_bounds__(256) void conv_kernel(const float* __restrict__ Wfc,
                                                   _Float16* __restrict__ W2t)
{
    int i = blockIdx.x * 256 + threadIdx.x;        // destination index
    if (i < NPAD * KDIM) {
        int nk = i / BTILE_ELE;                    // k-tile index
        int r  = i - nk * BTILE_ELE;
        int n  = r >> 5;                           // 0..319 output row
        int kc = r & 31;
        int p  = nk * 32 + kc;                     // logical k
        _Float16 v = (_Float16)0.0f;
        if (n < NOUT) {
            int s = p >> 4, rr = p & 15;
            int src = (rr < 8) ? p : ((TSTEPS - 1 - s) * 16 + rr);
            v = (_Float16)Wfc[n * KDIM + src];
        }
        W2t[i] = v;
    }
}

// ---------------- Kernel 3: out[rows,276] = H[rows,4416] * W2t^T + bfc ------
// R5: GBM=128 with 512 threads (8 waves, wave tile 32x160 unchanged) ->
// 256 blocks, B L2/L3 volume halves to 706 MB. 4-deep counted-vmcnt pipe
// (4 x 28KB LDS = 112KB, 1 block/CU, 2 waves/SIMD). Staging: 28 x 1KB slots;
// waves 0-3 take 4 slots (1 A + 3 B), waves 4-7 take 3 (1 A + 2 B); vmcnt
// literals are wave-uniform branched (steady 12/9, drain 12/9, 8/6, 4/3, 0).
// XOR source-swizzle + cq read-swizzle identical to R4.
__global__ __launch_bounds__(512, 2) void gemm_kernel(
    const _Float16* __restrict__ H, const _Float16* __restrict__ W2,
    const float* __restrict__ bfc, float* __restrict__ out)
{
    __shared__ char smem[4][BUFB];                 // per buf: A 8KB @0, B 20KB @8192

    const int tid  = threadIdx.x;
    const int lane = tid & 63;
    const int w    = tid >> 6;                     // 0..7
    const int wm   = w >> 1;                       // 32-row stripe (0..3)
    const int wn   = w & 1;                        // 160-col half
    const int m0   = blockIdx.x * GBM;
    const int l15  = lane & 15;
    const int l4   = lane >> 4;
    const int sel  = (l15 >> 1) & 3;               // row-derived swizzle selector
    const int cq   = (l4 ^ sel) << 4;              // swizzled 16B chunk offset in 64B row
    const bool wlow = (w < 4);                     // wave-uniform

    // base of this block's 128-row tile stripe in the tiled H layout
    const char* __restrict__ Htile = (const char*)(H + (size_t)(m0 >> 7) * ROWBLK_ELE);

    // ---- precomputed stage sources (linear LDS dest; source holds the
    // involution chunk ^ ((row>>1)&3); constant byte stride per k-chunk) ----
    const int lrow = lane >> 2;                    // row within 1KB slot
    const int lc   = lane & 3;                     // 16B chunk within 64B row
    // A slot j = w: source row rA in [0,128)
    const int rA = (w << 4) | lrow;
    const char* pA = Htile + rA * 64 + ((lc ^ ((rA >> 1) & 3)) << 4);
    const int dA = w << 10;
    // B slots j = w+8, w+16, (w<4: w+24): source row nr in [0,320)
    const char* pB[3];
    int dB[3];
    #pragma unroll
    for (int i = 0; i < 3; ++i) {
        const int j  = w + 8 * (i + 1);
        const int jj = (j < 28) ? j : 8;           // clamp (unused slot for w>=4)
        const int nr = ((jj - 8) << 4) | lrow;
        pB[i] = (const char*)W2 + nr * 64 + ((lc ^ ((nr >> 1) & 3)) << 4);
        dB[i] = jj << 10;
    }

    f32x4 acc[2][10] = {};

    auto stage = [&](int ck, char* buf) {
        async_copy16(pA + (size_t)ck * 8192, buf + dA);
        async_copy16(pB[0] + (size_t)ck * 20480, buf + dB[0]);
        async_copy16(pB[1] + (size_t)ck * 20480, buf + dB[1]);
        if (wlow) async_copy16(pB[2] + (size_t)ck * 20480, buf + dB[2]);
    };

    half8 af[2], bf[10];
    auto load_frags = [&](const char* buf) {
        const char* A  = buf;
        const char* Bb = buf + 8192;
        #pragma unroll
        for (int mi = 0; mi < 2; ++mi)
            af[mi] = *(const half8*)(A + (wm * 32 + mi * 16 + l15) * 64 + cq);
        #pragma unroll
        for (int ni = 0; ni < 10; ++ni)
            bf[ni] = *(const half8*)(Bb + (wn * 160 + ni * 16 + l15) * 64 + cq);
    };
    auto do_mfma = [&]() {
        #pragma unroll
        for (int ni = 0; ni < 10; ++ni) {
            #pragma unroll
            for (int mi = 0; mi < 2; ++mi)
                acc[mi][ni] = __builtin_amdgcn_mfma_f32_16x16x32_f16(af[mi], bf[ni], acc[mi][ni], 0, 0, 0);
        }
    };

    #define WAITVM(N) asm volatile("s_waitcnt vmcnt(" #N ")" ::: "memory")
    #define WAITLG()  asm volatile("s_waitcnt lgkmcnt(0)" ::: "memory")

    // prologue: fill the 4-deep pipe (16/12 loads in flight per wave)
    stage(0, smem[0]);
    stage(1, smem[1]);
    stage(2, smem[2]);
    stage(3, smem[3]);

    #pragma unroll 1
    for (int ck = 0; ck < NCHUNK - 4; ++ck) {
        char* buf = smem[0] + (size_t)(ck & 3) * BUFB;
        if (wlow) { WAITVM(12); } else { WAITVM(9); }  // own chunk-ck loads done
        __builtin_amdgcn_s_barrier();              // everyone's chunk ck in LDS
        load_frags(buf);                           // 12x ds_read_b128 -> regs
        WAITLG();                                  // reads committed before overwrite
        __builtin_amdgcn_s_barrier();              // all waves done reading buf
        stage(ck + 4, buf);                        // refill with chunk ck+4
        __builtin_amdgcn_sched_barrier(0);         // keep stage issued before MFMAs
        do_mfma();                                 // 20 MFMAs hide staging latency
    }
    // tail: chunks 134..137 live in bufs 2,3,0,1 — drain 3L -> 2L -> L -> 0
    if (wlow) { WAITVM(12); } else { WAITVM(9); }
    __builtin_amdgcn_s_barrier(); load_frags(smem[2]); do_mfma();
    if (wlow) { WAITVM(8); } else { WAITVM(6); }
    __builtin_amdgcn_s_barrier(); load_frags(smem[3]); do_mfma();
    if (wlow) { WAITVM(4); } else { WAITVM(3); }
    __builtin_amdgcn_s_barrier(); load_frags(smem[0]); do_mfma();
    WAITVM(0);
    __builtin_amdgcn_s_barrier(); load_frags(smem[1]); do_mfma();

    #undef WAITVM
    #undef WAITLG

    // C layout (16x16): col = lane&15, row = (lane>>4)*4 + reg
    #pragma unroll
    for (int ni = 0; ni < 10; ++ni) {
        const int n = wn * 160 + ni * 16 + l15;
        if (n < NOUT) {
            const float bv = bfc[n];
            #pragma unroll
            for (int mi = 0; mi < 2; ++mi) {
                const int mbase = m0 + wm * 32 + mi * 16 + l4 * 4;
                #pragma unroll
                for (int g = 0; g < 4; ++g)
                    out[(size_t)(mbase + g) * NOUT + n] = acc[mi][ni][g] + bv;
            }
        }
    }
}

extern "C" void kernel_launch(void* const* d_in, const int* in_sizes, int n_in,
                              void* d_out, int out_size, void* d_ws, size_t ws_size,
                              hipStream_t stream) {
    const float* x     = (const float*)d_in[0];
    const float* Wih_f = (const float*)d_in[1];
    const float* Whh_f = (const float*)d_in[2];
    const float* bih_f = (const float*)d_in[3];
    const float* bhh_f = (const float*)d_in[4];
    const float* Wih_b = (const float*)d_in[5];
    const float* Whh_b = (const float*)d_in[6];
    const float* bih_b = (const float*)d_in[7];
    const float* bhh_b = (const float*)d_in[8];
    const float* Wfc   = (const float*)d_in[9];
    const float* bfc   = (const float*)d_in[10];
    float* out = (float*)d_out;

    // Workspace layout: [W2t: NPAD*KDIM fp16][H chunk (tiled): chunk*KDIM fp16]
    _Float16* W2 = (_Float16*)d_ws;
    size_t h_off = ((size_t)NPAD * KDIM * 2 + 255) & ~(size_t)255;
    size_t avail = (ws_size > h_off) ? (ws_size - h_off) : 0;
    long maxrows = (long)(avail / ((size_t)KDIM * 2));
    int chunk = (int)((maxrows / 128) * 128);
    if (chunk > NBATCH) chunk = NBATCH;
    if (chunk < 128)    chunk = 128;
    _Float16* Hc = (_Float16*)((char*)d_ws + h_off);

    conv_kernel<<<(NPAD * KDIM + 255) / 256, 256, 0, stream>>>(Wfc, W2);

    for (int r0 = 0; r0 < NBATCH; r0 += chunk) {
        int rows = NBATCH - r0; if (rows > chunk) rows = chunk;
        lstm_kernel<<<rows / 16, 256, 0, stream>>>(x, Wih_f, Whh_f, bih_f, bhh_f,
                                                   Wih_b, Whh_b, bih_b, bhh_b,
                                                   r0, Hc);
        gemm_kernel<<<rows / 128, 512, 0, stream>>>(Hc, W2, bfc,
                                                    out + (size_t)r0 * NOUT);
    }
}